// Round 10
// baseline (2352.230 us; speedup 1.0000x reference)
//
#include <hip/hip_runtime.h>
#include <math.h>
#include <stdint.h>

#define BB 32
#define TT 1024
#define HH 128
#define G4 512   // 4*H
#define CH 16    // LSTM steps per LDS chunk
#define XPS 516  // xp row stride (floats): mult of 4 (b128 align)

typedef _Float16 half2_t __attribute__((ext_vector_type(2)));
typedef _Float16 half8_t __attribute__((ext_vector_type(8)));
typedef float f32x4 __attribute__((ext_vector_type(4)));
typedef __attribute__((address_space(3))) uint32_t lds_u32;
typedef __attribute__((address_space(1))) const uint32_t glb_u32;

__device__ __forceinline__ float fdot2f(half2_t a, half2_t b, float c) {
    return __builtin_amdgcn_fdot2(a, b, c, false);
}
__device__ __forceinline__ float rcpf(float x) {
    return __builtin_amdgcn_rcpf(x);
}
// quad_perm DPP moves: VALU pipe, no LDS traffic (quads = 4 consecutive lanes)
__device__ __forceinline__ float dpp_xor1(float x) {
    return __builtin_bit_cast(float, __builtin_amdgcn_update_dpp(
        0, __builtin_bit_cast(int, x), 0xB1, 0xF, 0xF, true));
}
__device__ __forceinline__ float dpp_xor2(float x) {
    return __builtin_bit_cast(float, __builtin_amdgcn_update_dpp(
        0, __builtin_bit_cast(int, x), 0x4E, 0xF, 0xF, true));
}
// workgroup barrier draining ONLY lgkmcnt — global/DMA loads (vmcnt) stay in flight
__device__ __forceinline__ void bar_lgkm() {
    asm volatile("s_waitcnt lgkmcnt(0)\n\ts_barrier" ::: "memory");
}

// =============== one-shot: w_ih (NL x 2 x 512 x 256 fp32) -> f16 ===============
__global__ __launch_bounds__(256) void cvt_wih(
    const float* __restrict__ w, _Float16* __restrict__ o)
{
    const int i = (blockIdx.x * 256 + threadIdx.x) * 4;   // 512*256*4 = 524288 exact
    float4 f = *(const float4*)(w + i);
    half2_t t[2] = { half2_t{(_Float16)f.x, (_Float16)f.y},
                     half2_t{(_Float16)f.z, (_Float16)f.w} };
    *(float2*)(o + i) = *(float2*)t;
}

// =============== Fused LSTM layer: 4-wave (256-thread) restructure ===============
// R8/R9 post-mortem: 512-thread blocks force 2 waves/SIMD -> hard 256-reg/wave
// budget -> W panel (needs ~260+) MUST spill. At 256 threads (4 waves, 1/SIMD,
// LDS 107KB -> 1 block/CU) the budget is 512 regs/wave: panel fits.
// Recurrence re-derived for 4 waves: quad owns j0=2q, j0+1 (2 h elements);
// per-SIMD VALU issue unchanged (1 wave x 128 fdot2 vs 2 waves x 64), wave-level
// DS instrs HALVE (shared hs read covers both j; one half2 h-write + one float2
// obuf write per quad), barrier syncs 4 waves not 8.
// Projection: wave owns 128 cols; W panel = 64 half8 = 256 regs loaded once;
// zero per-step vmem (raw-x via async global_load_lds -> xstage, drained once
// per chunk). Steady step: 2 xg b128 + 4 hs b128 + 0.5 afrag b128 + 4 MFMA.
__global__ __attribute__((amdgpu_waves_per_eu(1, 1))) __launch_bounds__(256)
void lstm_fused(
    const float* __restrict__ x_in,       // B x T x 256 (layer input)
    const _Float16* __restrict__ wih16_l, // 2 x 512 x 256 (this layer, f16)
    const float* __restrict__ b_ih_l,     // 2 x 512
    const float* __restrict__ b_hh_l,     // 2 x 512
    const float* __restrict__ w_hh_l,     // 2 x 512 x 128
    float* __restrict__ out)              // B x T x 256  ([fwd|bwd] concat)
{
    const int b = blockIdx.x & 31;
    const int d = blockIdx.x >> 5;
    const int tid = threadIdx.x;          // 0..255
    const int wvid = tid >> 6;            // 0..3
    const int l = tid & 63;
    const int s = l & 3;                  // k-slice within quad
    const int q = (wvid << 4) | (l >> 2); // 0..63 : quad id
    const int j0 = q << 1;                // this quad owns h[j0], h[j0+1]

    __shared__ __align__(16) _Float16 hs[HH];
    __shared__ __align__(16) float xp[2][CH * XPS];      // 66 KB gate-interleaved preacts
    __shared__ __align__(16) half2_t xr[2][CH * 128];    // 16 KB raw x in f16 (swizzled)
    __shared__ __align__(16) float obuf[CH * HH];        // 8 KB h output buffer
    __shared__ __align__(16) float xstage[CH * 256];     // 16 KB raw fp32 DMA staging

    // ---- recurrence weights: 8 gate-rows (2j x 4G), k in [32s,32s+32) = 128 regs ----
    half2_t wv[2][4][16];
#pragma unroll
    for (int jj = 0; jj < 2; ++jj)
#pragma unroll
    for (int G = 0; G < 4; ++G) {
        const float* wr = w_hh_l + (size_t)(d * G4 + 128 * G + j0 + jj) * HH + 32 * s;
#pragma unroll
        for (int q4 = 0; q4 < 8; ++q4) {
            float4 f = *(const float4*)(wr + 4 * q4);
            wv[jj][G][2 * q4]     = half2_t{(_Float16)f.x, (_Float16)f.y};
            wv[jj][G][2 * q4 + 1] = half2_t{(_Float16)f.z, (_Float16)f.w};
        }
    }

    // ---- projection setup: wave owns cols [wvid*128, +128) ----
    const int acol0 = (wvid << 7) + (l & 15);
    const _Float16* wn = wih16_l + ((size_t)d * G4 + acol0) * 256 + (l >> 4) * 8;
    float bias[8];
    int cix[8];
#pragma unroll
    for (int m = 0; m < 8; ++m) {
        const int n = acol0 + 16 * m;
        bias[m] = b_ih_l[d * G4 + n] + b_hh_l[d * G4 + n];
        cix[m] = ((n & 127) << 2) + (n >> 7);   // gate-interleaved store index
    }

    // ---- W_ih panel in regs: 8 n-tiles x 8 k-tiles = 64 half8 = 256 regs ----
    half8_t wf[8][8];
#pragma unroll
    for (int m = 0; m < 8; ++m)
#pragma unroll
    for (int kt = 0; kt < 8; ++kt)
        wf[m][kt] = *(const half8_t*)(wn + m * 4096 + kt * 32);

    const float* xbase = x_in + (size_t)b * TT * 256;

    // A-frag addressing: logical byte = row*512 + kt*64 + (l>>4)*16, row = l&15
    const int a_noswz = (l & 15) * 512 + (l >> 4) * 16;
    const int a_swz   = (l & 7) << 4;
    // conversion-store swizzle: thread writes 32B at tid*32 (row = tid>>4)
    const int cw_swz  = ((tid >> 4) & 7) << 4;

    // ---- prologue: stage raw chunks 0,1 -> xr (swizzled), via registers ----
#pragma unroll 1
    for (int p = 0; p < 2; ++p) {
        const int tlo = d ? (1008 - p * CH) : p * CH;
        const float* gs = xbase + (size_t)tlo * 256 + tid * 16;
        float4 f[4];
#pragma unroll
        for (int i = 0; i < 4; ++i) f[i] = *(const float4*)(gs + 4 * i);
        half2_t t8[8];
#pragma unroll
        for (int i = 0; i < 4; ++i) {
            t8[2 * i]     = half2_t{(_Float16)f[i].x, (_Float16)f[i].y};
            t8[2 * i + 1] = half2_t{(_Float16)f[i].z, (_Float16)f[i].w};
        }
        *(float4*)((char*)xr[p] + ((tid * 32) ^ cw_swz))      = *(float4*)&t8[0];
        *(float4*)((char*)xr[p] + ((tid * 32 + 16) ^ cw_swz)) = *(float4*)&t8[4];
    }
    __syncthreads();

    f32x4 acc[8];
#pragma unroll
    for (int m = 0; m < 8; ++m) acc[m] = (f32x4){bias[m], bias[m], bias[m], bias[m]};

    // ---- chunk-0 projection: straight-line 8 ktiles x 8 ntiles ----
#pragma unroll
    for (int kt = 0; kt < 8; ++kt) {
        half8_t af = *(const half8_t*)((const char*)xr[0] + ((a_noswz + kt * 64) ^ a_swz));
#pragma unroll
        for (int m = 0; m < 8; ++m)
            acc[m] = __builtin_amdgcn_mfma_f32_16x16x32_f16(af, wf[m][kt], acc[m], 0, 0, 0);
    }
    {
        const int rb = (l >> 4) * 4;
#pragma unroll
        for (int m = 0; m < 8; ++m)
#pragma unroll
        for (int qq = 0; qq < 4; ++qq)
            xp[0][(rb + qq) * XPS + cix[m]] = acc[m][qq];
    }
#pragma unroll
    for (int m = 0; m < 8; ++m) acc[m] = (f32x4){bias[m], bias[m], bias[m], bias[m]};

    if (tid < 64) ((half2_t*)hs)[tid] = half2_t{(_Float16)0.f, (_Float16)0.f};
    float c0 = 0.f, c1 = 0.f;   // quad-replicated cell states for j0, j0+1
    float* ob = out + (size_t)b * TT * 256 + d * HH;
    __syncthreads();   // xp[0], hs visible

#pragma unroll 1
    for (int ck = 0; ck < 64; ++ck) {
        const int cur = ck & 1;
        const bool doproj = (ck + 1 < 64);
        // async DMA raw x of chunk ck+2 -> xstage (vmcnt survives bar_lgkm;
        // drained once before the conversion at chunk end)
        if (ck + 2 < 64) {
            const int tlo2 = d ? (1008 - (ck + 2) * CH) : (ck + 2) * CH;
            const float* gsrc = xbase + (size_t)tlo2 * 256;
#pragma unroll
            for (int cc = 0; cc < 4; ++cc)
                __builtin_amdgcn_global_load_lds(
                    (glb_u32*)(gsrc + tid * 4 + cc * 1024),
                    (lds_u32*)&xstage[tid * 4 + cc * 1024],
                    16, 0, 0);
        }
        const float* xb = xp[cur];
        const char* xr_rd = (const char*)xr[cur ^ 1];   // raw x of chunk ck+1

        // one recurrence step: both j's of this quad
        auto rec_step = [&](int si) {
            const int lds_t = d ? (CH - 1 - si) : si;
            const float4 xgA = *(const float4*)&xb[lds_t * XPS + (j0 << 2)];
            const float4 xgB = *(const float4*)&xb[lds_t * XPS + (j0 << 2) + 4];

            const float4* hp = (const float4*)(hs + 32 * s);
            float4 hA = hp[0], hB = hp[1], hC = hp[2], hD = hp[3];
            half2_t hh[16];
            hh[0]  = __builtin_bit_cast(half2_t, hA.x);
            hh[1]  = __builtin_bit_cast(half2_t, hA.y);
            hh[2]  = __builtin_bit_cast(half2_t, hA.z);
            hh[3]  = __builtin_bit_cast(half2_t, hA.w);
            hh[4]  = __builtin_bit_cast(half2_t, hB.x);
            hh[5]  = __builtin_bit_cast(half2_t, hB.y);
            hh[6]  = __builtin_bit_cast(half2_t, hB.z);
            hh[7]  = __builtin_bit_cast(half2_t, hB.w);
            hh[8]  = __builtin_bit_cast(half2_t, hC.x);
            hh[9]  = __builtin_bit_cast(half2_t, hC.y);
            hh[10] = __builtin_bit_cast(half2_t, hC.z);
            hh[11] = __builtin_bit_cast(half2_t, hC.w);
            hh[12] = __builtin_bit_cast(half2_t, hD.x);
            hh[13] = __builtin_bit_cast(half2_t, hD.y);
            hh[14] = __builtin_bit_cast(half2_t, hD.z);
            hh[15] = __builtin_bit_cast(half2_t, hD.w);

            float A[2][4] = {}, E[2][4] = {};
#pragma unroll
            for (int kk = 0; kk < 8; ++kk) {
#pragma unroll
                for (int jj = 0; jj < 2; ++jj)
#pragma unroll
                for (int G = 0; G < 4; ++G) {
                    A[jj][G] = fdot2f(wv[jj][G][kk],     hh[kk],     A[jj][G]);
                    E[jj][G] = fdot2f(wv[jj][G][kk + 8], hh[kk + 8], E[jj][G]);
                }
            }
#pragma unroll
            for (int jj = 0; jj < 2; ++jj)
#pragma unroll
            for (int G = 0; G < 4; ++G) {
                float v = A[jj][G] + E[jj][G];
                v += dpp_xor1(v); v += dpp_xor2(v);
                A[jj][G] = v;
            }

            const float gi0 = rcpf(1.f + __expf(-(A[0][0] + xgA.x)));
            const float gf0 = rcpf(1.f + __expf(-(A[0][1] + xgA.y)));
            const float gg0 = 1.f - 2.f * rcpf(1.f + __expf(2.f * (A[0][2] + xgA.z)));
            const float go0 = rcpf(1.f + __expf(-(A[0][3] + xgA.w)));
            c0 = gf0 * c0 + gi0 * gg0;
            const float th0 = 1.f - 2.f * rcpf(1.f + __expf(2.f * c0));
            const float h0 = go0 * th0;

            const float gi1 = rcpf(1.f + __expf(-(A[1][0] + xgB.x)));
            const float gf1 = rcpf(1.f + __expf(-(A[1][1] + xgB.y)));
            const float gg1 = 1.f - 2.f * rcpf(1.f + __expf(2.f * (A[1][2] + xgB.z)));
            const float go1 = rcpf(1.f + __expf(-(A[1][3] + xgB.w)));
            c1 = gf1 * c1 + gi1 * gg1;
            const float th1 = 1.f - 2.f * rcpf(1.f + __expf(2.f * c1));
            const float h1 = go1 * th1;

            if (s == 0) {
                ((half2_t*)hs)[q] = half2_t{(_Float16)h0, (_Float16)h1};
                float2 ov; ov.x = h0; ov.y = h1;
                *(float2*)&obuf[si * HH + j0] = ov;
            }
        };

        // ---- 8 even/odd pairs, FULLY UNROLLED so wf indices are compile-time ----
#pragma unroll
        for (int sp = 0; sp < CH / 2; ++sp) {
            half8_t afrag = {};
            if (doproj)
                afrag = *(const half8_t*)(xr_rd + ((a_noswz + sp * 64) ^ a_swz));
            rec_step(2 * sp);
            if (doproj) {
#pragma unroll
                for (int m = 0; m < 4; ++m)
                    acc[m] = __builtin_amdgcn_mfma_f32_16x16x32_f16(afrag, wf[m][sp], acc[m], 0, 0, 0);
            }
            bar_lgkm();
            rec_step(2 * sp + 1);
            if (doproj) {
#pragma unroll
                for (int m = 4; m < 8; ++m)
                    acc[m] = __builtin_amdgcn_mfma_f32_16x16x32_f16(afrag, wf[m][sp], acc[m], 0, 0, 0);
            }
            bar_lgkm();
        }

        // flush obuf for chunk ck (coalesced, 8 floats/thread)
        {
            const int idx = tid * 8;
            const int sf = idx >> 7, jf = idx & 127;
            const int sg = ck * CH + sf;
            const int t  = d ? (TT - 1 - sg) : sg;
            float4 o0 = *(const float4*)&obuf[idx];
            float4 o1 = *(const float4*)&obuf[idx + 4];
            *(float4*)&ob[(size_t)t * 256 + jf]     = o0;
            *(float4*)&ob[(size_t)t * 256 + jf + 4] = o1;
        }
        // flush projected preacts (C frags, gate-interleaved) for chunk ck+1
        if (doproj) {
            float* xpn = xp[cur ^ 1];
            const int rb = (l >> 4) * 4;
#pragma unroll
            for (int m = 0; m < 8; ++m)
#pragma unroll
            for (int qq = 0; qq < 4; ++qq)
                xpn[(rb + qq) * XPS + cix[m]] = acc[m][qq];
#pragma unroll
            for (int m = 0; m < 8; ++m) acc[m] = (f32x4){bias[m], bias[m], bias[m], bias[m]};
        }
        // convert raw chunk ck+2 (xstage, DMA) -> xr[cur] (swizzled f16)
        if (ck + 2 < 64) {
            asm volatile("s_waitcnt vmcnt(0)" ::: "memory");   // DMA landed
            float4 f[4];
#pragma unroll
            for (int i = 0; i < 4; ++i) f[i] = *(const float4*)&xstage[tid * 16 + 4 * i];
            half2_t t8[8];
#pragma unroll
            for (int i = 0; i < 4; ++i) {
                t8[2 * i]     = half2_t{(_Float16)f[i].x, (_Float16)f[i].y};
                t8[2 * i + 1] = half2_t{(_Float16)f[i].z, (_Float16)f[i].w};
            }
            *(float4*)((char*)xr[cur] + ((tid * 32) ^ cw_swz))      = *(float4*)&t8[0];
            *(float4*)((char*)xr[cur] + ((tid * 32 + 16) ^ cw_swz)) = *(float4*)&t8[4];
        }
        __syncthreads();   // full drain: xp/xr/obuf/xstage handoff
    }
}

// =============== Attention (last-row only) + FC — 1024 threads ===============
__global__ __launch_bounds__(1024) void attn_kernel(
    const float* __restrict__ out1,  // B x T x 256
    const float* __restrict__ wq, const float* __restrict__ bq,
    const float* __restrict__ wk,
    const float* __restrict__ wv, const float* __restrict__ bv,
    const float* __restrict__ wfc, const float* __restrict__ bfc,
    float* __restrict__ outp)        // B x 4
{
    const int b = blockIdx.x;
    const int tid = threadIdx.x;
    const int n = tid & 255, qq = tid >> 8;   // col, quarter

    __shared__ float xl[256], q[256], u[256], cx[256];
    __shared__ __align__(16) float r[256];
    __shared__ float sc[TT];
    __shared__ float red[1024];
    __shared__ float part[4][256];

    const float* ob = out1 + (size_t)b * TT * 256;

    if (tid < 256) xl[tid] = ob[(size_t)(TT - 1) * 256 + tid];
    __syncthreads();

    // q[n] = bq[n] + xl . wq[n,:]
    {
        float a = 0.f;
        const float* wr = wq + (size_t)n * 256 + qq * 64;
        const float* xq = xl + qq * 64;
#pragma unroll 8
        for (int k = 0; k < 64; ++k) a += xq[k] * wr[k];
        part[qq][n] = a;
    }
    __syncthreads();
    if (tid < 256) q[tid] = bq[tid] + part[0][tid] + part[1][tid] + part[2][tid] + part[3][tid];
    __syncthreads();

    // r[n] = sum_d q[d] * wk[d,n]
    {
        float a = 0.f;
        const float* wkp = wk + (size_t)(qq * 64) * 256 + n;
#pragma unroll 8
        for (int dd = 0; dd < 64; ++dd) a += q[qq * 64 + dd] * wkp[(size_t)dd * 256];
        part[qq][n] = a;
    }
    __syncthreads();
    if (tid < 256) r[tid] = part[0][tid] + part[1][tid] + part[2][tid] + part[3][tid];
    __syncthreads();

    // scores: sc[t] = (r . out1[b,t,:]) / 16
    {
        const int wave = tid >> 6, lane = tid & 63;
        float4 r4 = *(const float4*)&r[lane * 4];
        for (int t = wave; t < TT; t += 16) {
            float4 o4 = *(const float4*)(ob + (size_t)t * 256 + lane * 4);
            float p = r4.x * o4.x + r4.y * o4.y + r4.z * o4.z + r4.w * o4.w;
#pragma unroll
            for (int off = 32; off > 0; off >>= 1) p += __shfl_down(p, off, 64);
            if (lane == 0) sc[t] = p * 0.0625f;
        }
    }
    __syncthreads();

    // softmax over sc[0..1023] — one element per thread
    float v = sc[tid];
    red[tid] = v; __syncthreads();
    for (int st = 512; st > 0; st >>= 1) {
        if (tid < st) red[tid] = fmaxf(red[tid], red[tid + st]);
        __syncthreads();
    }
    const float mx = red[0]; __syncthreads();
    const float e = expf(v - mx);
    sc[tid] = e;
    red[tid] = e; __syncthreads();
    for (int st = 512; st > 0; st >>= 1) {
        if (tid < st) red[tid] += red[tid + st];
        __syncthreads();
    }
    const float inv = 1.f / red[0];
    __syncthreads();

    // ctx: u[n] = inv * sum_t sc[t] * out1[b,t,n]
    {
        float a = 0.f;
        const float* op = ob + (size_t)(qq * 256) * 256 + n;
        const float* sp = sc + qq * 256;
#pragma unroll 4
        for (int t = 0; t < 256; ++t) a += sp[t] * op[(size_t)t * 256];
        part[qq][n] = a;
    }
    __syncthreads();
    if (tid < 256) u[tid] = (part[0][tid] + part[1][tid] + part[2][tid] + part[3][tid]) * inv;
    __syncthreads();

    // cx[n] = bv[n] + u . wv[n,:]
    {
        float a = 0.f;
        const float* wr = wv + (size_t)n * 256 + qq * 64;
#pragma unroll 8
        for (int k = 0; k < 64; ++k) a += u[qq * 64 + k] * wr[k];
        part[qq][n] = a;
    }
    __syncthreads();
    if (tid < 256) cx[tid] = bv[tid] + part[0][tid] + part[1][tid] + part[2][tid] + part[3][tid];
    __syncthreads();

    if (tid < 4) {
        float o = bfc[tid];
        for (int k = 0; k < 256; ++k) o += cx[k] * wfc[tid * 256 + k];
        outp[b * 4 + tid] = o;
    }
}

extern "C" void kernel_launch(void* const* d_in, const int* in_sizes, int n_in,
                              void* d_out, int out_size, void* d_ws, size_t ws_size,
                              hipStream_t stream)
{
    const float* x    = (const float*)d_in[0];
    const float* w_ih = (const float*)d_in[1];
    const float* w_hh = (const float*)d_in[2];
    const float* b_ih = (const float*)d_in[3];
    const float* b_hh = (const float*)d_in[4];
    const float* wq   = (const float*)d_in[5];
    const float* wk   = (const float*)d_in[6];
    const float* wv   = (const float*)d_in[7];
    const float* bq   = (const float*)d_in[8];
    const float* bv   = (const float*)d_in[10];
    const float* wfc  = (const float*)d_in[11];
    const float* bfcv = (const float*)d_in[12];
    float* outp = (float*)d_out;

    float* ws = (float*)d_ws;
    _Float16* wih16 = (_Float16*)ws;          // 2*2*512*256 f16 = 1 MB (262144 floats)
    float* out0 = ws + 262144;                // 8,388,608 floats (32 MB)
    float* out1 = out0 + 8388608;             // 8,388,608 floats (32 MB)

    // one-shot weight conversion: 2*2*512*256 = 524288 = 512*256*4
    cvt_wih<<<512, 256, 0, stream>>>(w_ih, wih16);

    lstm_fused<<<64, 256, 0, stream>>>(x, wih16, b_ih, b_hh, w_hh, out0);
    lstm_fused<<<64, 256, 0, stream>>>(out0, wih16 + 262144, b_ih + 1024, b_hh + 1024,
                                       w_hh + 2 * 512 * 128, out1);
    attn_kernel<<<32, 1024, 0, stream>>>(out1, wq, bq, wk, wv, bv, wfc, bfcv, outp);
}